// Round 3
// baseline (205.467 us; speedup 1.0000x reference)
//
#include <hip/hip_runtime.h>
#include <math.h>

#define B 64
#define T 4096
#define D 512
#define ROWS 128                 // t-rows per block
#define NCHK (T / ROWS)          // 32 chunks per batch row
#define WROWS 32                 // rows per wave

__device__ __forceinline__ float wave_sum64(float v) {
#pragma unroll
    for (int off = 32; off; off >>= 1)
        v += __shfl_xor(v, off, 64);
    return v;
}

// Fused kernel: per (b, 128-row chunk):
//   phase 1 (per wave, 32 rows): dot(key,q) via 8-row multiplexed butterfly,
//     g = mask ? exp(dot/sqrt(D)) : 0 -> attn (unnormalized), LDS, chunk sum.
//   phase 2 (per wave, same 32 rows): acc += g[t] * value[t,:] (g via in-wave
//     LDS broadcast, no barrier needed). One barrier at the end combines the
//     4 wave partials -> partial[blk][D]. Denominator applied in finalize.
__global__ __launch_bounds__(256) void fused_attn_kernel(const float* __restrict__ q,
                                                         const float* __restrict__ k,
                                                         const float* __restrict__ v,
                                                         const int* __restrict__ mask,
                                                         float* __restrict__ attn,
                                                         float* __restrict__ chunk_sums,
                                                         float* __restrict__ partial) {
    const float INV_SCALE = 0.04419417382415922f;  // 1/sqrt(512)

    __shared__ float sm_g[4 * WROWS];
    __shared__ float sm_part[4][D];
    __shared__ float sred[4];

    int blk = blockIdx.x;
    int b = blk >> 5;        // NCHK = 32 chunks per b
    int ch = blk & 31;
    int wave = threadIdx.x >> 6;
    int lane = threadIdx.x & 63;

    const float* qb = q + b * D;
    float4 qa = *(const float4*)(qb + lane * 4);
    float4 qc = *(const float4*)(qb + 256 + lane * 4);

    int wt0 = ch * ROWS + wave * WROWS;   // this wave's first t-row
    const float* kw = k + ((size_t)b * T + wt0) * D;

    // row owned by this lane after the 8-row butterfly: bits {5,4,3} -> {0,1,2}
    int r = ((lane >> 5) & 1) | (((lane >> 4) & 1) << 1) | (((lane >> 3) & 1) << 2);
    float gsum = 0.f;

#pragma unroll 1
    for (int grp = 0; grp < 4; ++grp) {
        const float* kg = kw + (size_t)(grp * 8) * D;
        float d8[8];
#pragma unroll
        for (int rr = 0; rr < 8; ++rr) {
            const float* kr = kg + (size_t)rr * D;
            float4 ka = *(const float4*)(kr + lane * 4);
            float4 kc = *(const float4*)(kr + 256 + lane * 4);
            d8[rr] = ka.x * qa.x + ka.y * qa.y + ka.z * qa.z + ka.w * qa.w
                   + kc.x * qc.x + kc.y * qc.y + kc.z * qc.z + kc.w * qc.w;
        }
        // multiplexed butterfly: 8 rows x 64 lanes -> full dots in 10 shuffles
        bool b5 = (lane & 32) != 0;
        float e[4];
#pragma unroll
        for (int i = 0; i < 4; ++i) {
            float u = b5 ? d8[2*i+1] : d8[2*i];
            float s = b5 ? d8[2*i]   : d8[2*i+1];
            e[i] = u + __shfl_xor(s, 32, 64);
        }
        bool b4 = (lane & 16) != 0;
        float f[2];
#pragma unroll
        for (int i = 0; i < 2; ++i) {
            float u = b4 ? e[2*i+1] : e[2*i];
            float s = b4 ? e[2*i]   : e[2*i+1];
            f[i] = u + __shfl_xor(s, 16, 64);
        }
        bool b3 = (lane & 8) != 0;
        float u = b3 ? f[1] : f[0];
        float s = b3 ? f[0] : f[1];
        float h = u + __shfl_xor(s, 8, 64);
        h += __shfl_xor(h, 4, 64);
        h += __shfl_xor(h, 2, 64);
        h += __shfl_xor(h, 1, 64);
        // h = dot for row r, replicated on 8 lanes (lane bits 2..0 free)

        int t = wt0 + grp * 8 + r;
        int m = mask[b * T + t];
        float g = m ? __expf(h * INV_SCALE) : 0.0f;
        gsum += g;
        if ((lane & 7) == 0) {
            sm_g[wave * WROWS + grp * 8 + r] = g;
            attn[(size_t)b * T + t] = g;   // unnormalized; finalize rescales
        }
    }
    // wave chunk-sum (each row's g replicated on 8 lanes -> /8)
    float ws = wave_sum64(gsum) * 0.125f;
    if (lane == 0) sred[wave] = ws;

    // phase 2: V accumulation over this wave's own 32 rows.
    // sm_g written by this same wave -> in-order LDS, no barrier needed.
    const float* vw = v + ((size_t)b * T + wt0) * D;
    float4 acc1 = {0,0,0,0}, acc2 = {0,0,0,0};
#pragma unroll 4
    for (int t = 0; t < WROWS; ++t) {
        float a = sm_g[wave * WROWS + t];
        float4 va = *(const float4*)(vw + (size_t)t * D + lane * 4);
        float4 vc = *(const float4*)(vw + (size_t)t * D + 256 + lane * 4);
        acc1.x += a * va.x; acc1.y += a * va.y; acc1.z += a * va.z; acc1.w += a * va.w;
        acc2.x += a * vc.x; acc2.y += a * vc.y; acc2.z += a * vc.z; acc2.w += a * vc.w;
    }
    *(float4*)(&sm_part[wave][lane * 4]) = acc1;
    *(float4*)(&sm_part[wave][256 + lane * 4]) = acc2;
    __syncthreads();

    int c0 = threadIdx.x * 2;
    float2 p;
    p.x = (sm_part[0][c0]     + sm_part[1][c0])     + (sm_part[2][c0]     + sm_part[3][c0]);
    p.y = (sm_part[0][c0 + 1] + sm_part[1][c0 + 1]) + (sm_part[2][c0 + 1] + sm_part[3][c0 + 1]);
    *(float2*)(partial + (size_t)blk * D + c0) = p;

    if (threadIdx.x == 0)
        chunk_sums[blk] = (sred[0] + sred[1]) + (sred[2] + sred[3]);
}

// Finalize: grid = B*4. Waves 0-1: reduce 32 partials for 128 ctx cols and
// apply 1/denom. Waves 2-3: normalize 1024 attn values in place.
// Denominator rebuilt identically (fixed-order butterfly) in every block.
__global__ __launch_bounds__(256) void finalize_kernel(const float* __restrict__ partial,
                                                       const float* __restrict__ chunk_sums,
                                                       float* __restrict__ attn,
                                                       float* __restrict__ ctx) {
    int blk = blockIdx.x;
    int b = blk >> 2;
    int sub = blk & 3;
    int tid = threadIdx.x;
    int lane = tid & 63;

    float cs = (lane < NCHK) ? chunk_sums[b * NCHK + lane] : 0.f;
    float denom = wave_sum64(cs);
    float inv = 1.0f / denom;

    if (tid < 128) {
        int c = sub * 128 + tid;
        float acc = 0.f;
#pragma unroll 8
        for (int j = 0; j < NCHK; ++j)
            acc += partial[((size_t)(b * NCHK + j)) * D + c];
        ctx[b * D + c] = acc * inv;
    } else {
        int s = tid - 128;
        size_t base = (size_t)b * T + sub * 1024 + (size_t)s * 8;
        float4 x = *(const float4*)(attn + base);
        float4 y = *(const float4*)(attn + base + 4);
        x.x *= inv; x.y *= inv; x.z *= inv; x.w *= inv;
        y.x *= inv; y.y *= inv; y.z *= inv; y.w *= inv;
        *(float4*)(attn + base) = x;
        *(float4*)(attn + base + 4) = y;
    }
}

extern "C" void kernel_launch(void* const* d_in, const int* in_sizes, int n_in,
                              void* d_out, int out_size, void* d_ws, size_t ws_size,
                              hipStream_t stream) {
    const float* q    = (const float*)d_in[0];
    const float* k    = (const float*)d_in[1];
    const float* v    = (const float*)d_in[2];
    const int*   mask = (const int*)d_in[3];

    float* ctx  = (float*)d_out;            // [B, D]
    float* attn = (float*)d_out + B * D;    // [B, T]

    float* chunk_sums = (float*)d_ws;            // B*NCHK = 2048 floats
    float* partial    = (float*)d_ws + 8192;     // [B*NCHK, D] = 4 MB

    fused_attn_kernel<<<B * NCHK, 256, 0, stream>>>(q, k, v, mask, attn, chunk_sums, partial);
    finalize_kernel<<<B * 4, 256, 0, stream>>>(partial, chunk_sums, attn, ctx);
}

// Round 4
// 124.989 us; speedup vs baseline: 1.6439x; 1.6439x over previous
//
#include <hip/hip_runtime.h>
#include <math.h>

#define B 64
#define T 4096
#define D 512
#define NCH 32            // t-chunks for context partials
#define CHT (T / NCH)     // 128 t per chunk

__device__ __forceinline__ float wave_sum64(float v) {
#pragma unroll
    for (int off = 32; off; off >>= 1)
        v += __shfl_xor(v, off, 64);
    return v;
}

// K1: attn_raw[b,t] = mask ? exp(key[b,t,:].query[b,:]/sqrt(D)) : 0 (exact),
// plus per-64-row chunk sums. grid = B*64, block = 256 (4 waves x 16 rows).
// KEY OPT: masked rows' K data is never loaded (wave-uniform s_cbranch via
// ballot bitmap) -> ~50% of the 512 MB K traffic skipped.
__global__ __launch_bounds__(256) void energy_exp_kernel(const float* __restrict__ q,
                                                         const float* __restrict__ k,
                                                         const int* __restrict__ mask,
                                                         float* __restrict__ attn,
                                                         float* __restrict__ chunk_sums) {
    const float INV_SCALE = 0.04419417382415922f;  // 1/sqrt(512)

    int blk = blockIdx.x;
    int b = blk >> 6;
    int chunk = blk & 63;
    int wave = threadIdx.x >> 6;
    int lane = threadIdx.x & 63;

    const float* qb = q + b * D;
    float4 qa = *(const float4*)(qb + lane * 4);
    float4 qc = *(const float4*)(qb + 256 + lane * 4);

    int t0 = chunk * 64 + wave * 16;
    const float* kbase = k + ((size_t)b * T + t0) * D;

    // 16-row mask bitmap, uniform across the wave (SGPR)
    int mv = (lane < 16) ? mask[b * T + t0 + lane] : 0;
    unsigned long long mbits = __ballot(mv != 0);

    // row owned by this lane after the 8-row butterfly: bits {5,4,3} -> {0,1,2}
    int r = ((lane >> 5) & 1) | (((lane >> 4) & 1) << 1) | (((lane >> 3) & 1) << 2);
    float gsum = 0.f;

#pragma unroll
    for (int grp = 0; grp < 2; ++grp) {
        float d8[8];
#pragma unroll
        for (int rr = 0; rr < 8; ++rr) {
            int row = grp * 8 + rr;
            d8[rr] = 0.f;
            if ((mbits >> row) & 1ull) {           // wave-uniform branch
                const float* kr = kbase + (size_t)row * D;
                float4 ka = *(const float4*)(kr + lane * 4);
                float4 kc = *(const float4*)(kr + 256 + lane * 4);
                d8[rr] = ka.x * qa.x + ka.y * qa.y + ka.z * qa.z + ka.w * qa.w
                       + kc.x * qc.x + kc.y * qc.y + kc.z * qc.z + kc.w * qc.w;
            }
        }
        // multiplexed butterfly: 8 rows x 64 lanes -> full dots in 10 shuffles
        bool b5 = (lane & 32) != 0;
        float e[4];
#pragma unroll
        for (int i = 0; i < 4; ++i) {
            float u = b5 ? d8[2*i+1] : d8[2*i];
            float s = b5 ? d8[2*i]   : d8[2*i+1];
            e[i] = u + __shfl_xor(s, 32, 64);
        }
        bool b4 = (lane & 16) != 0;
        float f[2];
#pragma unroll
        for (int i = 0; i < 2; ++i) {
            float u = b4 ? e[2*i+1] : e[2*i];
            float s = b4 ? e[2*i]   : e[2*i+1];
            f[i] = u + __shfl_xor(s, 16, 64);
        }
        bool b3 = (lane & 8) != 0;
        float u = b3 ? f[1] : f[0];
        float s = b3 ? f[0] : f[1];
        float h = u + __shfl_xor(s, 8, 64);
        h += __shfl_xor(h, 4, 64);
        h += __shfl_xor(h, 2, 64);
        h += __shfl_xor(h, 1, 64);
        // h = dot for row (grp*8 + r), replicated on 8 lanes

        int row = grp * 8 + r;
        int t = t0 + row;
        float g = ((mbits >> row) & 1ull) ? __expf(h * INV_SCALE) : 0.0f;
        gsum += g;
        if ((lane & 7) == 0)
            attn[(size_t)b * T + t] = g;   // unnormalized; K3 rescales in place
    }

    // wave chunk-sum (each row's g replicated on 8 lanes -> /8)
    float ws = wave_sum64(gsum) * 0.125f;
    __shared__ float sred[4];
    if (lane == 0) sred[wave] = ws;
    __syncthreads();
    if (threadIdx.x == 0)
        chunk_sums[blk] = (sred[0] + sred[1]) + (sred[2] + sred[3]);
}

// K3: context partials + in-place attn normalization. grid = B*NCH, block 256.
// Two t-streams x 128 threads x float4 covers D=512.
// KEY OPT: a==0 (exactly the masked rows) -> skip the V row load entirely.
// Denominator rebuilt per block from 64 chunk sums via identical fixed-order
// butterfly -> bitwise-deterministic and equal across blocks.
__global__ __launch_bounds__(256) void context_partial_kernel(float* __restrict__ attn,
                                                              const float* __restrict__ v,
                                                              const float* __restrict__ chunk_sums,
                                                              float* __restrict__ partial) {
    int blk = blockIdx.x;
    int b = blk >> 5;       // NCH = 32
    int ch = blk & 31;
    int tid = threadIdx.x;
    int lane = tid & 63;

    float cs = chunk_sums[b * 64 + lane];
    float denom = wave_sum64(cs);
    float inv = 1.0f / denom;

    int par = tid >> 7;            // which of 2 interleaved t-streams
    int dcol = (tid & 127) * 4;    // float4 column
    const float* vb = v + ((size_t)b * T + ch * CHT + par) * D + dcol;
    const float* ab = attn + (size_t)b * T + ch * CHT + par;

    float4 acc = {0.f, 0.f, 0.f, 0.f};
#pragma unroll 4
    for (int tt = 0; tt < CHT / 2; ++tt) {
        float a = ab[2 * tt];          // wave-uniform scalar
        if (a != 0.0f) {               // masked row -> no V load
            float4 vv = *(const float4*)(vb + (size_t)(2 * tt) * D);
            acc.x += a * vv.x; acc.y += a * vv.y;
            acc.z += a * vv.z; acc.w += a * vv.w;
        }
    }
    acc.x *= inv; acc.y *= inv; acc.z *= inv; acc.w *= inv;
    *(float4*)(partial + ((size_t)(b * 64 + ch * 2 + par)) * D + dcol) = acc;

    __syncthreads();               // all attn reads done before overwrite
    if (tid < CHT) {
        size_t idx = (size_t)b * T + ch * CHT + tid;
        attn[idx] *= inv;
    }
}

// K4: reduce 64 partial rows -> context. grid = B, block = 256.
__global__ __launch_bounds__(256) void context_reduce_kernel(const float* __restrict__ partial,
                                                             float* __restrict__ ctx) {
    int b = blockIdx.x;
    int tid = threadIdx.x;
    int d0 = tid * 2;
    float2 acc = {0.f, 0.f};
#pragma unroll 8
    for (int j = 0; j < 64; ++j) {
        float2 p = *(const float2*)(partial + ((size_t)(b * 64 + j)) * D + d0);
        acc.x += p.x;
        acc.y += p.y;
    }
    *(float2*)(ctx + (size_t)b * D + d0) = acc;
}

extern "C" void kernel_launch(void* const* d_in, const int* in_sizes, int n_in,
                              void* d_out, int out_size, void* d_ws, size_t ws_size,
                              hipStream_t stream) {
    const float* q    = (const float*)d_in[0];
    const float* k    = (const float*)d_in[1];
    const float* v    = (const float*)d_in[2];
    const int*   mask = (const int*)d_in[3];

    float* ctx  = (float*)d_out;            // [B, D]
    float* attn = (float*)d_out + B * D;    // [B, T]

    float* chunk_sums = (float*)d_ws;            // B*64 floats = 16 KB
    float* partial    = (float*)d_ws + 8192;     // [B*64, D] = 8.4 MB

    energy_exp_kernel<<<B * 64, 256, 0, stream>>>(q, k, mask, attn, chunk_sums);
    context_partial_kernel<<<B * NCH, 256, 0, stream>>>(attn, v, chunk_sums, partial);
    context_reduce_kernel<<<B, 256, 0, stream>>>(partial, ctx);
}

// Round 5
// 115.918 us; speedup vs baseline: 1.7725x; 1.0783x over previous
//
#include <hip/hip_runtime.h>
#include <math.h>

#define B 64
#define T 4096
#define D 512
#define NCH 32            // t-chunks for context partials
#define CHT (T / NCH)     // 128 t per chunk

__device__ __forceinline__ float wave_sum64(float v) {
#pragma unroll
    for (int off = 32; off; off >>= 1)
        v += __shfl_xor(v, off, 64);
    return v;
}

// K1: attn_raw[b,t] = mask ? exp(key[b,t,:].query[b,:]/sqrt(D)) : 0 (exact),
// plus per-64-row chunk sums. grid = B*64, block = 256 (4 waves x 16 rows).
// Masked rows' K data is never loaded (wave-uniform s_cbranch via ballot
// bitmap) -> ~50% of the 512 MB K traffic skipped.
__global__ __launch_bounds__(256) void energy_exp_kernel(const float* __restrict__ q,
                                                         const float* __restrict__ k,
                                                         const int* __restrict__ mask,
                                                         float* __restrict__ attn,
                                                         float* __restrict__ chunk_sums) {
    const float INV_SCALE = 0.04419417382415922f;  // 1/sqrt(512)

    int blk = blockIdx.x;
    int b = blk >> 6;
    int chunk = blk & 63;
    int wave = threadIdx.x >> 6;
    int lane = threadIdx.x & 63;

    const float* qb = q + b * D;
    float4 qa = *(const float4*)(qb + lane * 4);
    float4 qc = *(const float4*)(qb + 256 + lane * 4);

    int t0 = chunk * 64 + wave * 16;
    const float* kbase = k + ((size_t)b * T + t0) * D;

    // 16-row mask bitmap, uniform across the wave (SGPR)
    int mv = (lane < 16) ? mask[b * T + t0 + lane] : 0;
    unsigned long long mbits = __ballot(mv != 0);

    // row owned by this lane after the 8-row butterfly: bits {5,4,3} -> {0,1,2}
    int r = ((lane >> 5) & 1) | (((lane >> 4) & 1) << 1) | (((lane >> 3) & 1) << 2);
    float gsum = 0.f;

#pragma unroll
    for (int grp = 0; grp < 2; ++grp) {
        float d8[8];
#pragma unroll
        for (int rr = 0; rr < 8; ++rr) {
            int row = grp * 8 + rr;
            d8[rr] = 0.f;
            if ((mbits >> row) & 1ull) {           // wave-uniform branch
                const float* kr = kbase + (size_t)row * D;
                float4 ka = *(const float4*)(kr + lane * 4);
                float4 kc = *(const float4*)(kr + 256 + lane * 4);
                d8[rr] = ka.x * qa.x + ka.y * qa.y + ka.z * qa.z + ka.w * qa.w
                       + kc.x * qc.x + kc.y * qc.y + kc.z * qc.z + kc.w * qc.w;
            }
        }
        // multiplexed butterfly: 8 rows x 64 lanes -> full dots in 10 shuffles
        bool b5 = (lane & 32) != 0;
        float e[4];
#pragma unroll
        for (int i = 0; i < 4; ++i) {
            float u = b5 ? d8[2*i+1] : d8[2*i];
            float s = b5 ? d8[2*i]   : d8[2*i+1];
            e[i] = u + __shfl_xor(s, 32, 64);
        }
        bool b4 = (lane & 16) != 0;
        float f[2];
#pragma unroll
        for (int i = 0; i < 2; ++i) {
            float u = b4 ? e[2*i+1] : e[2*i];
            float s = b4 ? e[2*i]   : e[2*i+1];
            f[i] = u + __shfl_xor(s, 16, 64);
        }
        bool b3 = (lane & 8) != 0;
        float u = b3 ? f[1] : f[0];
        float s = b3 ? f[0] : f[1];
        float h = u + __shfl_xor(s, 8, 64);
        h += __shfl_xor(h, 4, 64);
        h += __shfl_xor(h, 2, 64);
        h += __shfl_xor(h, 1, 64);
        // h = dot for row (grp*8 + r), replicated on 8 lanes

        int row = grp * 8 + r;
        int t = t0 + row;
        float g = ((mbits >> row) & 1ull) ? __expf(h * INV_SCALE) : 0.0f;
        gsum += g;
        if ((lane & 7) == 0)
            attn[(size_t)b * T + t] = g;   // unnormalized; K3 rescales in place
    }

    // wave chunk-sum (each row's g replicated on 8 lanes -> /8)
    float ws = wave_sum64(gsum) * 0.125f;
    __shared__ float sred[4];
    if (lane == 0) sred[wave] = ws;
    __syncthreads();
    if (threadIdx.x == 0)
        chunk_sums[blk] = (sred[0] + sred[1]) + (sred[2] + sred[3]);
}

// K3: context partials + in-place attn normalization. grid = B*NCH, block 256.
// 2 t-streams (waves 0,1 / 2,3) x 128 lanes x float4 covers D=512.
// RESTRUCTURE: stage attn chunk in LDS, wave-compact non-zero rows into a
// dense (row, a) register list -> V gather loop is unconditional with
// SGPR loop bound -> deep load pipelining (no attn->branch->load chain).
// Compaction is order-stable -> accumulation order identical to before.
__global__ __launch_bounds__(256) void context_partial_kernel(float* __restrict__ attn,
                                                              const float* __restrict__ v,
                                                              const float* __restrict__ chunk_sums,
                                                              float* __restrict__ partial) {
    __shared__ float sa[CHT];
    __shared__ int   sm_c[4][64];
    __shared__ float sm_a[4][64];

    int blk = blockIdx.x;
    int b = blk >> 5;       // NCH = 32
    int ch = blk & 31;
    int tid = threadIdx.x;
    int wave = tid >> 6;
    int lane = tid & 63;

    float cs = chunk_sums[b * 64 + lane];
    float denom = wave_sum64(cs);
    float inv = 1.0f / denom;

    if (tid < CHT) sa[tid] = attn[(size_t)b * T + ch * CHT + tid];
    __syncthreads();

    int par = wave >> 1;               // t-stream: rows 2*i+par
    int dcol = ((wave & 1) * 64 + lane) * 4;

    // compact this stream's non-zero rows (lane i examines row 2*i+par)
    int myrow = 2 * lane + par;
    float mya0 = sa[myrow];
    unsigned long long ball = __ballot(mya0 != 0.0f);
    int cnt = __popcll(ball);
    int pre = __popcll(ball & ((1ull << lane) - 1ull));
    if (mya0 != 0.0f) {
        sm_c[wave][pre] = myrow;
        sm_a[wave][pre] = mya0;
    }
    __syncthreads();

    int  crow = sm_c[wave][lane];      // compacted row index held per lane
    float ca  = sm_a[wave][lane];

    const float* vb = v + ((size_t)b * T + ch * CHT) * D + dcol;

    float4 acc = {0.f, 0.f, 0.f, 0.f};
#pragma unroll 4
    for (int j = 0; j < cnt; ++j) {
        int row = __shfl(crow, j, 64);
        float a = __shfl(ca, j, 64);
        float4 vv = *(const float4*)(vb + (size_t)row * D);
        acc.x += a * vv.x; acc.y += a * vv.y;
        acc.z += a * vv.z; acc.w += a * vv.w;
    }
    acc.x *= inv; acc.y *= inv; acc.z *= inv; acc.w *= inv;
    *(float4*)(partial + ((size_t)(b * 64 + ch * 2 + par)) * D + dcol) = acc;

    // in-place attn normalization from the staged copy
    if (tid < CHT)
        attn[(size_t)b * T + ch * CHT + tid] = sa[tid] * inv;
}

// K4: reduce 64 partial rows -> context. grid = B, block = 256.
__global__ __launch_bounds__(256) void context_reduce_kernel(const float* __restrict__ partial,
                                                             float* __restrict__ ctx) {
    int b = blockIdx.x;
    int tid = threadIdx.x;
    int d0 = tid * 2;
    float2 acc = {0.f, 0.f};
#pragma unroll 8
    for (int j = 0; j < 64; ++j) {
        float2 p = *(const float2*)(partial + ((size_t)(b * 64 + j)) * D + d0);
        acc.x += p.x;
        acc.y += p.y;
    }
    *(float2*)(ctx + (size_t)b * D + d0) = acc;
}

extern "C" void kernel_launch(void* const* d_in, const int* in_sizes, int n_in,
                              void* d_out, int out_size, void* d_ws, size_t ws_size,
                              hipStream_t stream) {
    const float* q    = (const float*)d_in[0];
    const float* k    = (const float*)d_in[1];
    const float* v    = (const float*)d_in[2];
    const int*   mask = (const int*)d_in[3];

    float* ctx  = (float*)d_out;            // [B, D]
    float* attn = (float*)d_out + B * D;    // [B, T]

    float* chunk_sums = (float*)d_ws;            // B*64 floats = 16 KB
    float* partial    = (float*)d_ws + 8192;     // [B*64, D] = 8.4 MB

    energy_exp_kernel<<<B * 64, 256, 0, stream>>>(q, k, mask, attn, chunk_sums);
    context_partial_kernel<<<B * NCH, 256, 0, stream>>>(attn, v, chunk_sums, partial);
    context_reduce_kernel<<<B, 256, 0, stream>>>(partial, ctx);
}